// Round 2
// baseline (213.157 us; speedup 1.0000x reference)
//
#include <hip/hip_runtime.h>
#include <stdint.h>

#define B_N   8
#define C_N   256
#define H_N   96
#define W_N   128
#define NCK   8          // C_N / 32
#define ND    21
#define NK    (ND * ND)  // 441

typedef __attribute__((ext_vector_type(8))) short short8;
typedef __attribute__((ext_vector_type(4))) float f32x4;

// 12-KB zero block (.bss, zero-initialized at load, never written) for OOB dy rows
__device__ char zchunk[12288];

__device__ __forceinline__ uint32_t f2bf(float f) {
  uint32_t u = __builtin_bit_cast(uint32_t, f);
  return (u + 0x7fffu + ((u >> 16) & 1u)) >> 16;   // RNE
}
__device__ __forceinline__ uint32_t packbf(float lo, float hi) {
  return f2bf(lo) | (f2bf(hi) << 16);
}

// ---------------- merged prepass: fp32 NCHW -> bf16 fragment-linear layouts ----------------
// Apre per (bi,ck): 8 KB.  u32 idx = ((t*2+p)<<8) + lane*4 + e2
//   lane = m + 16*kg ; holds A[je=16t+m][cm=kg*8+e][parity p] = in1[c][i][j=32t+2m+p]
// Bpre per (by,ck): 12 KB. u32 idx = ((s*2+p)<<8) + lane*4 + e2
//   holds in2[c][y][x = 32s+2m-20+p], zero when x out of range
__global__ __launch_bounds__(256) void prep(const float* __restrict__ in1,
                                            const float* __restrict__ in2,
                                            unsigned short* __restrict__ Apre,
                                            unsigned short* __restrict__ Bpre) {
  __shared__ float tile[32][W_N + 1];
  int blk = blockIdx.x;
  bool isA = blk < 6144;
  int rblk = isA ? blk : blk - 6144;
  int ck = rblk & 7, bi = rblk >> 3;
  int b = bi / H_N, row = bi % H_N;
  const float* src = (isA ? in1 : in2) + ((size_t)(b * C_N + ck * 32) * H_N + row) * W_N;
  int tid = threadIdx.x;
  for (int idx = tid; idx < 32 * W_N; idx += 256) {
    int c = idx >> 7, j = idx & 127;
    tile[c][j] = src[(size_t)c * (H_N * W_N) + j];
  }
  __syncthreads();
  if (isA) {
    uint32_t* dst = (uint32_t*)Apre + (size_t)rblk * 2048;
    for (int q = tid; q < 2048; q += 256) {
      int e2 = q & 3, ln = (q >> 2) & 63, tp = q >> 8;
      int t = tp >> 1, p = tp & 1;
      int m = ln & 15, kg = ln >> 4;
      int c0 = kg * 8 + 2 * e2;
      int j = 32 * t + 2 * m + p;
      dst[q] = packbf(tile[c0][j], tile[c0 + 1][j]);
    }
  } else {
    uint32_t* dst = (uint32_t*)Bpre + (size_t)rblk * 3072;
    for (int q = tid; q < 3072; q += 256) {
      int e2 = q & 3, ln = (q >> 2) & 63, sp = q >> 8;
      int s = sp >> 1, p = sp & 1;
      int m = ln & 15, kg = ln >> 4;
      int c0 = kg * 8 + 2 * e2;
      int x = 32 * s + 2 * m - 20 + p;
      dst[q] = ((unsigned)x < 128u) ? packbf(tile[c0][x], tile[c0 + 1][x]) : 0u;
    }
  }
}

// ---------------- main: barrier-free K loop, fragments loaded directly from global ----------
__global__ __launch_bounds__(256, 3) void corr_main(const unsigned short* __restrict__ Apre,
                                                    const unsigned short* __restrict__ Bpre,
                                                    float* __restrict__ out) {
  __shared__ float outl[ND][W_N + 1];   // 10836 B epilogue buffer

  int h = blockIdx.x;
  int l = (h & 7) * 672 + (h >> 3);     // XCD-chunked remap (5376 = 8*672, bijective)
  int bi = l / 7, gidx = l - 7 * bi;
  int b = bi / H_N, i = bi % H_N;
  int dyb = gidx * 3;

  int tid = threadIdx.x;
  int lane = tid & 63, w = tid >> 6;    // 4 waves: (parity p, t-half th)
  int p = w & 1, th = w >> 1;
  int m = lane & 15, kg = lane >> 4;

  f32x4 acc[2][3][3];                   // [tt][g][delta]
#pragma unroll
  for (int a0i = 0; a0i < 2; ++a0i)
#pragma unroll
    for (int a1i = 0; a1i < 3; ++a1i)
#pragma unroll
      for (int a2i = 0; a2i < 3; ++a2i) acc[a0i][a1i][a2i] = {0.f, 0.f, 0.f, 0.f};

  // per-wave fragment base pointers (chunk 0)
  const char* Ap = (const char*)Apre + (size_t)bi * 65536
                   + (((4 * th + p)) << 10) + lane * 16;          // t=2th ; a1 at +2048
  const char* Bp[3];
  int bstr[3];
#pragma unroll
  for (int g = 0; g < 3; ++g) {
    int y = i + 2 * (dyb + g) - 20;
    bool v = (unsigned)y < (unsigned)H_N;
    const char* base = v ? (const char*)Bpre + (size_t)(b * H_N + y) * 98304
                         : (const char*)zchunk;
    Bp[g] = base + ((4 * th + p) << 10) + lane * 16;              // s=2th ; +ss*2048
    bstr[g] = v ? 12288 : 0;
  }

#pragma unroll 2
  for (int ck = 0; ck < NCK; ++ck) {
    short8 a0 = *(const short8*)(Ap);
    short8 a1 = *(const short8*)(Ap + 2048);
    short8 bb[4][3];
#pragma unroll
    for (int ss = 0; ss < 4; ++ss)
#pragma unroll
      for (int g = 0; g < 3; ++g)
        bb[ss][g] = *(const short8*)(Bp[g] + ss * 2048);
#pragma unroll
    for (int ss = 0; ss < 4; ++ss)
#pragma unroll
      for (int g = 0; g < 3; ++g) {
        if (ss <= 2) acc[0][g][ss]     = __builtin_amdgcn_mfma_f32_16x16x32_bf16(a0, bb[ss][g], acc[0][g][ss], 0, 0, 0);
        if (ss >= 1) acc[1][g][ss - 1] = __builtin_amdgcn_mfma_f32_16x16x32_bf16(a1, bb[ss][g], acc[1][g][ss - 1], 0, 0, 0);
      }
    Ap += 8192;
    Bp[0] += bstr[0]; Bp[1] += bstr[1]; Bp[2] += bstr[2];
  }

  // ---- epilogue: band-extract via LDS, coalesced stores
#pragma unroll
  for (int g = 0; g < 3; ++g) {
    __syncthreads();
#pragma unroll
    for (int tt = 0; tt < 2; ++tt) {
      int t = 2 * th + tt;
#pragma unroll
      for (int dl = 0; dl < 3; ++dl) {
#pragma unroll
        for (int r = 0; r < 4; ++r) {
          int a_ = kg * 4 + r;               // je within t-tile (C row)
          int dxi = 16 * dl + m - a_;        // C col n = m
          if (dxi >= 0 && dxi <= 20) {
            int j = 2 * (16 * t + a_) + p;
            outl[dxi][j] = acc[tt][g][dl][r];
          }
        }
      }
    }
    __syncthreads();
    int dyi = dyb + g;
    size_t obase = ((size_t)(b * NK + dyi * ND) * H_N + i) * W_N;
    for (int idx = tid; idx < ND * W_N; idx += 256) {
      int dxi = idx >> 7, j = idx & 127;
      out[obase + (size_t)dxi * (H_N * W_N) + j] = outl[dxi][j];
    }
  }
}

// ---------------- fallback (only if workspace too small) ----------------
__global__ void corr_naive(const float* __restrict__ in1, const float* __restrict__ in2,
                           float* __restrict__ out) {
  size_t o = (size_t)blockIdx.x * 256 + threadIdx.x;
  const size_t total = (size_t)B_N * NK * H_N * W_N;
  if (o >= total) return;
  int j = o & 127;
  int i = (int)((o >> 7) % H_N);
  int k = (int)((o / ((size_t)H_N * W_N)) % NK);
  int b = (int)(o / ((size_t)NK * H_N * W_N));
  int dyi = k / ND, dxi = k % ND;
  int y = i + 2 * dyi - 20, x = j + 2 * dxi - 20;
  float s = 0.f;
  if ((unsigned)y < (unsigned)H_N && (unsigned)x < (unsigned)W_N) {
    const float* p1 = in1 + ((size_t)b * C_N * H_N + i) * W_N + j;
    const float* p2 = in2 + ((size_t)b * C_N * H_N + y) * W_N + x;
    for (int c = 0; c < C_N; ++c)
      s += p1[(size_t)c * H_N * W_N] * p2[(size_t)c * H_N * W_N];
  }
  out[o] = s;
}

extern "C" void kernel_launch(void* const* d_in, const int* in_sizes, int n_in,
                              void* d_out, int out_size, void* d_ws, size_t ws_size,
                              hipStream_t stream) {
  const float* in1 = (const float*)d_in[0];
  const float* in2 = (const float*)d_in[1];
  float* out = (float*)d_out;

  const size_t A_BYTES = (size_t)6144 * 8192;    // 50,331,648
  const size_t B_BYTES = (size_t)6144 * 12288;   // 75,497,472
  if (ws_size < A_BYTES + B_BYTES) {
    size_t total = (size_t)B_N * NK * H_N * W_N;
    corr_naive<<<(int)((total + 255) / 256), 256, 0, stream>>>(in1, in2, out);
    return;
  }
  unsigned short* Apre = (unsigned short*)d_ws;
  unsigned short* Bpre = (unsigned short*)((char*)d_ws + A_BYTES);

  prep<<<12288, 256, 0, stream>>>(in1, in2, Apre, Bpre);
  corr_main<<<5376, 256, 0, stream>>>(Apre, Bpre, out);
}

// Round 3
// 208.273 us; speedup vs baseline: 1.0234x; 1.0234x over previous
//
#include <hip/hip_runtime.h>
#include <stdint.h>

#define B_N   8
#define C_N   256
#define H_N   96
#define W_N   128
#define NCK   8          // C_N / 32
#define ND    21
#define NK    (ND * ND)  // 441

typedef __attribute__((ext_vector_type(8))) short short8;
typedef __attribute__((ext_vector_type(4))) float f32x4;

// 12-KB zero block (.bss, zero-initialized at load, never written) for OOB dy rows
__device__ char zchunk[12288];

__device__ __forceinline__ uint32_t f2bf(float f) {
  uint32_t u = __builtin_bit_cast(uint32_t, f);
  return (u + 0x7fffu + ((u >> 16) & 1u)) >> 16;   // RNE
}
__device__ __forceinline__ uint32_t packbf(float lo, float hi) {
  return f2bf(lo) | (f2bf(hi) << 16);
}

// ---------------- merged prepass: fp32 NCHW -> bf16 fragment-linear layouts ----------------
// Apre per (bi,ck): 8 KB.  u32 idx = ((t*2+p)<<8) + lane*4 + e2
//   lane = m + 16*kg ; holds A[je=16t+m][cm=kg*8+e][parity p] = in1[c][i][j=32t+2m+p]
// Bpre per (by,ck): 12 KB. u32 idx = ((s*2+p)<<8) + lane*4 + e2
//   holds in2[c][y][x = 32s+2m-20+p], zero when x out of range
__global__ __launch_bounds__(256) void prep(const float* __restrict__ in1,
                                            const float* __restrict__ in2,
                                            unsigned short* __restrict__ Apre,
                                            unsigned short* __restrict__ Bpre) {
  __shared__ float tile[32][W_N + 1];
  int blk = blockIdx.x;
  bool isA = blk < 6144;
  int rblk = isA ? blk : blk - 6144;
  int ck = rblk & 7, bi = rblk >> 3;
  int b = bi / H_N, row = bi % H_N;
  const float* src = (isA ? in1 : in2) + ((size_t)(b * C_N + ck * 32) * H_N + row) * W_N;
  int tid = threadIdx.x;
  for (int idx = tid; idx < 32 * W_N; idx += 256) {
    int c = idx >> 7, j = idx & 127;
    tile[c][j] = src[(size_t)c * (H_N * W_N) + j];
  }
  __syncthreads();
  if (isA) {
    uint32_t* dst = (uint32_t*)Apre + (size_t)rblk * 2048;
    for (int q = tid; q < 2048; q += 256) {
      int e2 = q & 3, ln = (q >> 2) & 63, tp = q >> 8;
      int t = tp >> 1, p = tp & 1;
      int m = ln & 15, kg = ln >> 4;
      int c0 = kg * 8 + 2 * e2;
      int j = 32 * t + 2 * m + p;
      dst[q] = packbf(tile[c0][j], tile[c0 + 1][j]);
    }
  } else {
    uint32_t* dst = (uint32_t*)Bpre + (size_t)rblk * 3072;
    for (int q = tid; q < 3072; q += 256) {
      int e2 = q & 3, ln = (q >> 2) & 63, sp = q >> 8;
      int s = sp >> 1, p = sp & 1;
      int m = ln & 15, kg = ln >> 4;
      int c0 = kg * 8 + 2 * e2;
      int x = 32 * s + 2 * m - 20 + p;
      dst[q] = ((unsigned)x < 128u) ? packbf(tile[c0][x], tile[c0 + 1][x]) : 0u;
    }
  }
}

// ---------------- main: barrier-free K loop, chain-ordered grid for L2 B-row reuse ----------
// Chain c = b*96 + i0, position q in [0,7): task (i = (i0+6q)%96, gidx = 6-q).
// Before wrap, B-rows are {i0+16+2g} — IDENTICAL for all 7 tasks of the chain.
// XCD-chunked: each XCD gets 96 whole chains (= one batch image b), dispatched in order.
__global__ __launch_bounds__(256, 3) void corr_main(const unsigned short* __restrict__ Apre,
                                                    const unsigned short* __restrict__ Bpre,
                                                    float* __restrict__ out) {
  __shared__ float outl[ND][W_N + 1];   // 10836 B epilogue buffer

  int h = blockIdx.x;
  int l = (h & 7) * 672 + (h >> 3);     // XCD-chunked remap (5376 = 8*672, bijective)
  int c = l / 7, q = l - 7 * c;         // chain, position
  int b = c / 96, i0 = c - 96 * b;
  int gidx = 6 - q;
  int i = i0 + 6 * q; if (i >= H_N) i -= H_N;
  int bi = b * H_N + i;
  int dyb = gidx * 3;

  int tid = threadIdx.x;
  int lane = tid & 63, w = tid >> 6;    // 4 waves: (parity p, t-half th)
  int p = w & 1, th = w >> 1;
  int m = lane & 15, kg = lane >> 4;

  f32x4 acc[2][3][3];                   // [tt][g][delta]
#pragma unroll
  for (int a0i = 0; a0i < 2; ++a0i)
#pragma unroll
    for (int a1i = 0; a1i < 3; ++a1i)
#pragma unroll
      for (int a2i = 0; a2i < 3; ++a2i) acc[a0i][a1i][a2i] = {0.f, 0.f, 0.f, 0.f};

  // per-wave fragment base pointers (chunk 0)
  const char* Ap = (const char*)Apre + (size_t)bi * 65536
                   + (((4 * th + p)) << 10) + lane * 16;          // t=2th ; a1 at +2048
  const char* Bp[3];
  int bstr[3];
#pragma unroll
  for (int g = 0; g < 3; ++g) {
    int y = i + 2 * (dyb + g) - 20;
    bool v = (unsigned)y < (unsigned)H_N;
    const char* base = v ? (const char*)Bpre + (size_t)(b * H_N + y) * 98304
                         : (const char*)zchunk;
    Bp[g] = base + ((4 * th + p) << 10) + lane * 16;              // s=2th ; +ss*2048
    bstr[g] = v ? 12288 : 0;
  }

#pragma unroll 2
  for (int ck = 0; ck < NCK; ++ck) {
    short8 a0 = *(const short8*)(Ap);
    short8 a1 = *(const short8*)(Ap + 2048);
    short8 bb[4][3];
#pragma unroll
    for (int ss = 0; ss < 4; ++ss)
#pragma unroll
      for (int g = 0; g < 3; ++g)
        bb[ss][g] = *(const short8*)(Bp[g] + ss * 2048);
#pragma unroll
    for (int ss = 0; ss < 4; ++ss)
#pragma unroll
      for (int g = 0; g < 3; ++g) {
        if (ss <= 2) acc[0][g][ss]     = __builtin_amdgcn_mfma_f32_16x16x32_bf16(a0, bb[ss][g], acc[0][g][ss], 0, 0, 0);
        if (ss >= 1) acc[1][g][ss - 1] = __builtin_amdgcn_mfma_f32_16x16x32_bf16(a1, bb[ss][g], acc[1][g][ss - 1], 0, 0, 0);
      }
    Ap += 8192;
    Bp[0] += bstr[0]; Bp[1] += bstr[1]; Bp[2] += bstr[2];
  }

  // ---- epilogue: band-extract via LDS, coalesced stores
#pragma unroll
  for (int g = 0; g < 3; ++g) {
    __syncthreads();
#pragma unroll
    for (int tt = 0; tt < 2; ++tt) {
      int t = 2 * th + tt;
#pragma unroll
      for (int dl = 0; dl < 3; ++dl) {
#pragma unroll
        for (int r = 0; r < 4; ++r) {
          int a_ = kg * 4 + r;               // je within t-tile (C row)
          int dxi = 16 * dl + m - a_;        // C col n = m
          if (dxi >= 0 && dxi <= 20) {
            int j = 2 * (16 * t + a_) + p;
            outl[dxi][j] = acc[tt][g][dl][r];
          }
        }
      }
    }
    __syncthreads();
    int dyi = dyb + g;
    size_t obase = ((size_t)(b * NK + dyi * ND) * H_N + i) * W_N;
    for (int idx = tid; idx < ND * W_N; idx += 256) {
      int dxi = idx >> 7, j = idx & 127;
      out[obase + (size_t)dxi * (H_N * W_N) + j] = outl[dxi][j];
    }
  }
}

// ---------------- fallback (only if workspace too small) ----------------
__global__ void corr_naive(const float* __restrict__ in1, const float* __restrict__ in2,
                           float* __restrict__ out) {
  size_t o = (size_t)blockIdx.x * 256 + threadIdx.x;
  const size_t total = (size_t)B_N * NK * H_N * W_N;
  if (o >= total) return;
  int j = o & 127;
  int i = (int)((o >> 7) % H_N);
  int k = (int)((o / ((size_t)H_N * W_N)) % NK);
  int b = (int)(o / ((size_t)NK * H_N * W_N));
  int dyi = k / ND, dxi = k % ND;
  int y = i + 2 * dyi - 20, x = j + 2 * dxi - 20;
  float s = 0.f;
  if ((unsigned)y < (unsigned)H_N && (unsigned)x < (unsigned)W_N) {
    const float* p1 = in1 + ((size_t)b * C_N * H_N + i) * W_N + j;
    const float* p2 = in2 + ((size_t)b * C_N * H_N + y) * W_N + x;
    for (int c = 0; c < C_N; ++c)
      s += p1[(size_t)c * H_N * W_N] * p2[(size_t)c * H_N * W_N];
  }
  out[o] = s;
}

extern "C" void kernel_launch(void* const* d_in, const int* in_sizes, int n_in,
                              void* d_out, int out_size, void* d_ws, size_t ws_size,
                              hipStream_t stream) {
  const float* in1 = (const float*)d_in[0];
  const float* in2 = (const float*)d_in[1];
  float* out = (float*)d_out;

  const size_t A_BYTES = (size_t)6144 * 8192;    // 50,331,648
  const size_t B_BYTES = (size_t)6144 * 12288;   // 75,497,472
  if (ws_size < A_BYTES + B_BYTES) {
    size_t total = (size_t)B_N * NK * H_N * W_N;
    corr_naive<<<(int)((total + 255) / 256), 256, 0, stream>>>(in1, in2, out);
    return;
  }
  unsigned short* Apre = (unsigned short*)d_ws;
  unsigned short* Bpre = (unsigned short*)((char*)d_ws + A_BYTES);

  prep<<<12288, 256, 0, stream>>>(in1, in2, Apre, Bpre);
  corr_main<<<5376, 256, 0, stream>>>(Apre, Bpre, out);
}

// Round 4
// 200.381 us; speedup vs baseline: 1.0638x; 1.0394x over previous
//
#include <hip/hip_runtime.h>
#include <stdint.h>

#define B_N   8
#define C_N   256
#define H_N   96
#define W_N   128
#define NCK   8          // C_N / 32
#define ND    21
#define NK    (ND * ND)  // 441

typedef __attribute__((ext_vector_type(8))) short short8;
typedef __attribute__((ext_vector_type(4))) float f32x4;

__device__ __forceinline__ uint32_t f2bf(float f) {
  uint32_t u = __builtin_bit_cast(uint32_t, f);
  return (u + 0x7fffu + ((u >> 16) & 1u)) >> 16;   // RNE
}
__device__ __forceinline__ uint32_t packbf(float lo, float hi) {
  return f2bf(lo) | (f2bf(hi) << 16);
}
__device__ __forceinline__ void async16(void* lds_dst, const void* gsrc) {
  __builtin_amdgcn_global_load_lds(
      (const __attribute__((address_space(1))) void*)gsrc,
      (__attribute__((address_space(3))) void*)lds_dst, 16, 0, 0);
}

// ---------------- merged prepass: fp32 NCHW -> bf16 fragment-linear layouts ----------------
// Apre per (bi,ck): 8 KB.  u32 idx = ((t*2+p)<<8) + lane*4 + e2 ; lane = m + 16*kg
//   holds in1[c=kg*8+2e2(+1)][i][j=32t+2m+p]
// Bpre per (by,ck): 12 KB. u32 idx = ((s*2+p)<<8) + lane*4 + e2
//   holds in2[c][y][x = 32s+2m-20+p], zero when x out of range
__global__ __launch_bounds__(256) void prep(const float* __restrict__ in1,
                                            const float* __restrict__ in2,
                                            unsigned short* __restrict__ Apre,
                                            unsigned short* __restrict__ Bpre) {
  __shared__ float tile[32][W_N + 1];
  int blk = blockIdx.x;
  bool isA = blk < 6144;
  int rblk = isA ? blk : blk - 6144;
  int ck = rblk & 7, bi = rblk >> 3;
  int b = bi / H_N, row = bi % H_N;
  const float* src = (isA ? in1 : in2) + ((size_t)(b * C_N + ck * 32) * H_N + row) * W_N;
  int tid = threadIdx.x;
  for (int idx = tid; idx < 32 * W_N; idx += 256) {
    int c = idx >> 7, j = idx & 127;
    tile[c][j] = src[(size_t)c * (H_N * W_N) + j];
  }
  __syncthreads();
  if (isA) {
    uint32_t* dst = (uint32_t*)Apre + (size_t)rblk * 2048;
    for (int q = tid; q < 2048; q += 256) {
      int e2 = q & 3, ln = (q >> 2) & 63, tp = q >> 8;
      int t = tp >> 1, p = tp & 1;
      int m = ln & 15, kg = ln >> 4;
      int c0 = kg * 8 + 2 * e2;
      int j = 32 * t + 2 * m + p;
      dst[q] = packbf(tile[c0][j], tile[c0 + 1][j]);
    }
  } else {
    uint32_t* dst = (uint32_t*)Bpre + (size_t)rblk * 3072;
    for (int q = tid; q < 3072; q += 256) {
      int e2 = q & 3, ln = (q >> 2) & 63, sp = q >> 8;
      int s = sp >> 1, p = sp & 1;
      int m = ln & 15, kg = ln >> 4;
      int c0 = kg * 8 + 2 * e2;
      int x = 32 * s + 2 * m - 20 + p;
      dst[q] = ((unsigned)x < 128u) ? packbf(tile[c0][x], tile[c0 + 1][x]) : 0u;
    }
  }
}

// ---------------- main: chain-block, LDS-shared B across 3 chain elements ----------
// Chain Y = i + 6*gidx - 20 : every element shares B rows {Y, Y+2, Y+4}.
// Block = (b, Y, pos): elements gidx = g_min + 3*pos + rr, rr in {0,1,2}.
// 12 waves = (rr, p, th); per-chunk: stage B (36 KB, dbuf) + per-wave 2 A loads,
// 12 ds_read_b128, 18 MFMA. One barrier per chunk.
__global__ __launch_bounds__(768, 3) void corr_main(const unsigned short* __restrict__ Apre,
                                                    const unsigned short* __restrict__ Bpre,
                                                    float* __restrict__ out) {
  __shared__ __align__(16) char Bl[2][36864];   // 72 KB double-buffered B stage

  int h = blockIdx.x;
  int b = h & 7, blk = h >> 3;        // each XCD gets one batch image, blk ascending = Y ascending
  int Y, pos;
  if (blk < 18)       { Y = blk - 20;                pos = 0; }
  else if (blk < 54)  { int t = blk - 18;  Y = -2 + (t >> 1); pos = t & 1; }
  else if (blk < 234) { int t = blk - 54;  Y = 16 + t / 3;    pos = t % 3; }
  else if (blk < 270) { int t = blk - 234; Y = 76 + (t >> 1); pos = t & 1; }
  else                { Y = 94 + (blk - 270);        pos = 0; }
  int g_min = (Y > 75) ? (Y - 70) / 6 : 0;     // ceil((Y-75)/6)
  int g_max = (Y + 20) / 6; if (g_max > 6) g_max = 6;

  int tid = threadIdx.x;
  int lane = tid & 63, w = tid >> 6;           // 12 waves
  int rr = w >> 2, sub = w & 3;
  int p = sub & 1, th = sub >> 1;
  int m = lane & 15, kg = lane >> 4;

  int gidx = g_min + pos * 3 + rr;
  bool act = gidx <= g_max;
  int i_el = Y + 20 - 6 * gidx;                // in [0,96) when act
  int dyb = 3 * gidx;

  // B row sources for stage (wave-uniform); invalid rows stay zero in LDS
  const char* bsrc[3];
  bool yval[3];
#pragma unroll
  for (int k = 0; k < 3; ++k) {
    int y = Y + 2 * k;
    yval[k] = (unsigned)y < (unsigned)H_N;
    bsrc[k] = (const char*)Bpre + (size_t)((b * H_N + (yval[k] ? y : 0)) * NCK) * 12288
              + w * 1024 + lane * 16;
  }
  // zero invalid B rows in both buffers (stage layout addressing), then barrier
#pragma unroll
  for (int k = 0; k < 3; ++k) {
    if (!yval[k]) {
      short8 z = {};
      *(short8*)(&Bl[0][0] + k * 12288 + w * 1024 + lane * 16) = z;
      *(short8*)(&Bl[1][0] + k * 12288 + w * 1024 + lane * 16) = z;
    }
  }

  f32x4 acc[2][3][3];
#pragma unroll
  for (int a0i = 0; a0i < 2; ++a0i)
#pragma unroll
    for (int a1i = 0; a1i < 3; ++a1i)
#pragma unroll
      for (int a2i = 0; a2i < 3; ++a2i) acc[a0i][a1i][a2i] = {0.f, 0.f, 0.f, 0.f};

  const char* Ap = (const char*)Apre + (size_t)(b * H_N + (act ? i_el : 0)) * 65536
                   + ((4 * th + p) << 10) + lane * 16;

  // stage chunk 0 into buf0 (after zeroing: disjoint rows, but zero-writes are LDS ops
  // drained by the same __syncthreads below)
#pragma unroll
  for (int k = 0; k < 3; ++k)
    if (yval[k]) async16(&Bl[0][0] + k * 12288 + w * 1024, bsrc[k]);
  __syncthreads();

  for (int ck = 0; ck < NCK; ++ck) {
    char* cur = &Bl[ck & 1][0];
    // issue next chunk's stage into the other buffer
    if (ck < NCK - 1) {
      char* nxt = &Bl[(ck + 1) & 1][0];
#pragma unroll
      for (int k = 0; k < 3; ++k)
        if (yval[k]) async16(nxt + k * 12288 + w * 1024, bsrc[k] + (size_t)(ck + 1) * 12288);
    }
    if (act) {
      short8 a0 = *(const short8*)(Ap);
      short8 a1 = *(const short8*)(Ap + 2048);
#pragma unroll
      for (int ss = 0; ss < 4; ++ss) {
        int s = 2 * th + ss;
#pragma unroll
        for (int g = 0; g < 3; ++g) {
          short8 bbv = *(const short8*)(cur + g * 12288 + ((2 * s + p) << 10) + lane * 16);
          if (ss <= 2) acc[0][g][ss]     = __builtin_amdgcn_mfma_f32_16x16x32_bf16(a0, bbv, acc[0][g][ss], 0, 0, 0);
          if (ss >= 1) acc[1][g][ss - 1] = __builtin_amdgcn_mfma_f32_16x16x32_bf16(a1, bbv, acc[1][g][ss - 1], 0, 0, 0);
        }
      }
    }
    Ap += 8192;
    __syncthreads();   // drains stage loads (vmcnt) + orders buffer reuse
  }

  // ---- epilogue: per-rr-group band-extract via LDS (reuses Bl), coalesced stores
  float* outl = (float*)(&Bl[0][0] + rr * 11072);   // 3 * 11072 <= 73728 ; region [21][129] f32
  int gt = sub * 64 + lane;                          // thread index within rr-group [0,256)
#pragma unroll
  for (int g = 0; g < 3; ++g) {
    if (act) {
#pragma unroll
      for (int tt = 0; tt < 2; ++tt) {
        int t = 2 * th + tt;
#pragma unroll
        for (int dl = 0; dl < 3; ++dl) {
#pragma unroll
          for (int r = 0; r < 4; ++r) {
            int a_ = kg * 4 + r;
            int dxi = 16 * dl + m - a_;
            if (dxi >= 0 && dxi <= 20) {
              int j = 2 * (16 * t + a_) + p;
              outl[dxi * 129 + j] = acc[tt][g][dl][r];
            }
          }
        }
      }
    }
    __syncthreads();
    if (act) {
      int dyi = dyb + g;
      size_t obase = ((size_t)(b * NK + dyi * ND) * H_N + i_el) * W_N;
      for (int idx = gt; idx < ND * W_N; idx += 256) {
        int dxi = idx >> 7, j = idx & 127;
        out[obase + (size_t)dxi * (H_N * W_N) + j] = outl[dxi * 129 + j];
      }
    }
    __syncthreads();
  }
}

// ---------------- fallback (only if workspace too small) ----------------
__global__ void corr_naive(const float* __restrict__ in1, const float* __restrict__ in2,
                           float* __restrict__ out) {
  size_t o = (size_t)blockIdx.x * 256 + threadIdx.x;
  const size_t total = (size_t)B_N * NK * H_N * W_N;
  if (o >= total) return;
  int j = o & 127;
  int i = (int)((o >> 7) % H_N);
  int k = (int)((o / ((size_t)H_N * W_N)) % NK);
  int b = (int)(o / ((size_t)NK * H_N * W_N));
  int dyi = k / ND, dxi = k % ND;
  int y = i + 2 * dyi - 20, x = j + 2 * dxi - 20;
  float s = 0.f;
  if ((unsigned)y < (unsigned)H_N && (unsigned)x < (unsigned)W_N) {
    const float* p1 = in1 + ((size_t)b * C_N * H_N + i) * W_N + j;
    const float* p2 = in2 + ((size_t)b * C_N * H_N + y) * W_N + x;
    for (int c = 0; c < C_N; ++c)
      s += p1[(size_t)c * H_N * W_N] * p2[(size_t)c * H_N * W_N];
  }
  out[o] = s;
}

extern "C" void kernel_launch(void* const* d_in, const int* in_sizes, int n_in,
                              void* d_out, int out_size, void* d_ws, size_t ws_size,
                              hipStream_t stream) {
  const float* in1 = (const float*)d_in[0];
  const float* in2 = (const float*)d_in[1];
  float* out = (float*)d_out;

  const size_t A_BYTES = (size_t)6144 * 8192;    // 50,331,648
  const size_t B_BYTES = (size_t)6144 * 12288;   // 75,497,472
  if (ws_size < A_BYTES + B_BYTES) {
    size_t total = (size_t)B_N * NK * H_N * W_N;
    corr_naive<<<(int)((total + 255) / 256), 256, 0, stream>>>(in1, in2, out);
    return;
  }
  unsigned short* Apre = (unsigned short*)d_ws;
  unsigned short* Bpre = (unsigned short*)((char*)d_ws + A_BYTES);

  prep<<<12288, 256, 0, stream>>>(in1, in2, Apre, Bpre);
  corr_main<<<2304, 768, 0, stream>>>(Apre, Bpre, out);
}